// Round 10
// baseline (726.057 us; speedup 1.0000x reference)
//
#include <hip/hip_runtime.h>
#include <stdint.h>
#include <math.h>

#define B_    8
#define S_    1024
#define D_    576
#define H_    9
#define HD_   64
#define LAT_  144
#define FF_   1536
#define NE_   7
#define NT_   8192
#define NPAIR_ 16384
#define NACT_  24576
#define MAXT_ 200

typedef unsigned short u16;
typedef __attribute__((ext_vector_type(8))) short bf16x8;
typedef __attribute__((ext_vector_type(4))) float f32x4;
typedef __attribute__((ext_vector_type(4))) unsigned short us4;

__device__ __forceinline__ u16 f2b(float f){
  union{float f;uint32_t u;} v; v.f=f;
  uint32_t u=v.u;
  return (u16)((u + 0x7fffu + ((u>>16)&1u))>>16);
}
__device__ __forceinline__ float b2f(u16 h){
  union{uint32_t u;float f;} v; v.u=((uint32_t)h)<<16; return v.f;
}

#define MFMA16(a,b,c) __builtin_amdgcn_mfma_f32_16x16x32_bf16((a),(b),(c),0,0,0)

typedef __attribute__((address_space(1))) const unsigned char g_u8;
typedef __attribute__((address_space(3))) unsigned char s_u8;
__device__ __forceinline__ void gll16(const void* g, void* l){
  __builtin_amdgcn_global_load_lds((g_u8*)g, (s_u8*)l, 16, 0, 0);
}

// ---------------- MoE weight conversion fp32->bf16 ----------------
struct CvtSegs {
  const float* src[6];
  u16* dst[6];
  int start4[7];
};
__global__ void k_cvt(CvtSegs cs){
  int tot = cs.start4[6];
  for(int i = blockIdx.x*blockDim.x + threadIdx.x; i < tot; i += gridDim.x*blockDim.x){
    int s=0;
    #pragma unroll
    for(int j=0;j<6;j++) if(i >= cs.start4[j+1]) s=j+1;
    int loc = i - cs.start4[s];
    float4 v = ((const float4*)cs.src[s])[loc];
    us4 o; o[0]=f2b(v.x); o[1]=f2b(v.y); o[2]=f2b(v.z); o[3]=f2b(v.w);
    ((us4*)cs.dst[s])[loc] = o;
  }
}

// ---------------- attention weight conversion fp32 -> hi/lo bf16 -------
struct CvtSegs2 {
  const float* src[3];
  u16* dhi[3]; u16* dlo[3];
  int start4[4];
};
__global__ void k_cvt_split(CvtSegs2 cs){
  int tot = cs.start4[3];
  for(int i = blockIdx.x*blockDim.x + threadIdx.x; i < tot; i += gridDim.x*blockDim.x){
    int s=0;
    #pragma unroll
    for(int j=0;j<3;j++) if(i >= cs.start4[j+1]) s=j+1;
    int loc = i - cs.start4[s];
    float4 v = ((const float4*)cs.src[s])[loc];
    us4 oh, ol;
    float vv[4]={v.x,v.y,v.z,v.w};
    #pragma unroll
    for(int j=0;j<4;j++){ u16 hh=f2b(vv[j]); oh[j]=hh; ol[j]=f2b(vv[j]-b2f(hh)); }
    ((us4*)cs.dhi[s])[loc]=oh;
    ((us4*)cs.dlo[s])[loc]=ol;
  }
}

// up-proj weights [3][576][144] -> padded [3][576][160] hi/lo
__global__ void k_cvt_pad_split(const float* __restrict__ Wqu, const float* __restrict__ Wku,
                                const float* __restrict__ Wvu,
                                u16* __restrict__ dhi, u16* __restrict__ dlo){
  int i = blockIdx.x*256 + threadIdx.x;
  if(i >= 3*D_*160) return;
  int z = i/(D_*160); int rem = i - z*D_*160;
  int row = rem/160, col = rem - row*160;
  const float* s = (z==0)?Wqu:((z==1)?Wku:Wvu);
  float v = (col<LAT_)? s[row*LAT_+col] : 0.f;
  u16 hh=f2b(v);
  dhi[i]=hh; dlo[i]=f2b(v-b2f(hh));
}

// ---------------- RoPE tables ----------------
__global__ void k_rope_tab(float* __restrict__ cost, float* __restrict__ sint){
  int i = blockIdx.x*256+threadIdx.x; if(i>=S_*32) return;
  int s=i>>5, d=i&31;
  float pw = (float)pow(10000.0, (double)d/32.0);
  float inv = 1.0f/pw;
  float ang = (float)s*inv;
  cost[i]=cosf(ang); sint[i]=sinf(ang);
}

// ---------------- fp32 rmsnorm -> hi/lo bf16 ----------------
__global__ __launch_bounds__(64) void k_rms(const float* __restrict__ x, const float* __restrict__ w,
                      u16* __restrict__ hhi, u16* __restrict__ hlo){
  int t = blockIdx.x; int lane = threadIdx.x;
  const float* xr = x + (size_t)t*D_;
  float v[9]; float ss=0.f;
  #pragma unroll
  for(int j=0;j<9;j++){ v[j]=xr[lane+64*j]; ss += v[j]*v[j]; }
  #pragma unroll
  for(int m=1;m<64;m<<=1) ss += __shfl_xor(ss,m,64);
  float sc = 1.0f/sqrtf(ss/(float)D_ + 1e-5f);
  #pragma unroll
  for(int j=0;j<9;j++){
    float y = v[j]*sc*w[lane+64*j];
    size_t o=(size_t)t*D_+lane+64*j;
    u16 hh=f2b(y); hhi[o]=hh; hlo[o]=f2b(y-b2f(hh));
  }
}

// ---------------- fused rmsnorm2 + router (fp32 exact) -----------------
__global__ __launch_bounds__(256) void k_rms_router(const float* __restrict__ x2, const float* __restrict__ w,
                        const float* __restrict__ Wr, const float* __restrict__ rb,
                        u16* __restrict__ hb, int* __restrict__ idx2, float* __restrict__ w2){
  int wid=threadIdx.x>>6, lane=threadIdx.x&63;
  int t = blockIdx.x*4 + wid;
  const float* xr = x2 + (size_t)t*D_;
  float v[9]; float ss=0.f;
  #pragma unroll
  for(int j=0;j<9;j++){ v[j]=xr[lane+64*j]; ss += v[j]*v[j]; }
  #pragma unroll
  for(int m=1;m<64;m<<=1) ss += __shfl_xor(ss,m,64);
  float sc = 1.0f/sqrtf(ss/(float)D_ + 1e-5f);
  float hv[9];
  #pragma unroll
  for(int j=0;j<9;j++){
    float y = v[j]*sc*w[lane+64*j];
    hv[j]=y;
    hb[(size_t)t*D_+lane+64*j]=f2b(y);
  }
  float pr[7];
  #pragma unroll
  for(int e=0;e<7;e++){
    float s=0.f;
    #pragma unroll
    for(int j=0;j<9;j++) s += hv[j]*Wr[e*D_+lane+64*j];
    #pragma unroll
    for(int mm=1;mm<64;mm<<=1) s+=__shfl_xor(s,mm,64);
    pr[e] = 1.f/(1.f+expf(-(s+rb[e])));
  }
  int e0=0; float b0=pr[0];
  #pragma unroll
  for(int e=1;e<7;e++) if(pr[e]>b0){b0=pr[e];e0=e;}
  int e1=-1; float b1=-1e30f;
  #pragma unroll
  for(int e=0;e<7;e++) if(e!=e0 && pr[e]>b1){b1=pr[e];e1=e;}
  if(lane==0){
    float s=b0+b1;
    idx2[2*t]=e0; idx2[2*t+1]=e1;
    w2[2*t]=b0/s; w2[2*t+1]=b1/s;
  }
}

// ---------------- split-bf16 128x128 MFMA GEMM (dbuf + counted vmcnt) --
template<int EPI>
__global__ __launch_bounds__(256) void k_gemm2(
    const u16* __restrict__ Ahi, const u16* __restrict__ Alo, int lda, int aofs_z,
    const u16* __restrict__ Bhi, const u16* __restrict__ Blo, int ldb, long bStrideZ,
    int N, int ksteps,
    u16* __restrict__ Chi, u16* __restrict__ Clo, int ldc,
    float* __restrict__ C32, long cStrideZ, const float* __restrict__ resid)
{
  __shared__ u16 Ahs[2][128*32], Als[2][128*32], Bhs[2][128*32], Bls[2][128*32];
  int tid=threadIdx.x, wid=tid>>6, lane=tid&63;
  int m0=blockIdx.x*128, n0=blockIdx.y*128, z=blockIdx.z;
  const u16* Abh = Ahi + ((z>0)?aofs_z:0);
  const u16* Abl = Alo + ((z>0)?aofs_z:0);
  const u16* Bbh = Bhi + (long)z*bStrideZ;
  const u16* Bbl = Blo + (long)z*bStrideZ;
  int lq=lane&15, lg=lane>>4;
  int wr=wid>>1, wc=wid&1;
  // staging geometry: thread handles rows r0 and r0+64, 16B chunk sc8 (swizzled)
  int r0 = wid*16 + (lane>>2);
  int so = wid*1024 + lane*16;
  int sc8 = ((lane&3) ^ ((r0>>1)&3))*8;
  const u16* pah0 = Abh + (long)(m0+r0)*lda + sc8;
  const u16* pah1 = Abh + (long)(m0+64+r0)*lda + sc8;
  const u16* pal0 = Abl + (long)(m0+r0)*lda + sc8;
  const u16* pal1 = Abl + (long)(m0+64+r0)*lda + sc8;
  int br0 = n0+r0;    if(br0>N-1) br0=N-1;
  int br1 = n0+64+r0; if(br1>N-1) br1=N-1;
  const u16* pbh0 = Bbh + (long)br0*ldb + sc8;
  const u16* pbh1 = Bbh + (long)br1*ldb + sc8;
  const u16* pbl0 = Bbl + (long)br0*ldb + sc8;
  const u16* pbl1 = Bbl + (long)br1*ldb + sc8;
  #define STG(bi, kt_) do{ int ko=(kt_)*32;                \
    gll16(pah0+ko, (char*)Ahs[bi]+so);                     \
    gll16(pah1+ko, (char*)Ahs[bi]+4096+so);                \
    gll16(pal0+ko, (char*)Als[bi]+so);                     \
    gll16(pal1+ko, (char*)Als[bi]+4096+so);                \
    gll16(pbh0+ko, (char*)Bhs[bi]+so);                     \
    gll16(pbh1+ko, (char*)Bhs[bi]+4096+so);                \
    gll16(pbl0+ko, (char*)Bls[bi]+so);                     \
    gll16(pbl1+ko, (char*)Bls[bi]+4096+so); }while(0)
  f32x4 acc[4][4]={};
  STG(0,0);
  for(int kt=0;kt<ksteps;kt++){
    int cur=kt&1;
    if(kt+1<ksteps){ STG(cur^1, kt+1); asm volatile("s_waitcnt vmcnt(8)":::"memory"); }
    else           { asm volatile("s_waitcnt vmcnt(0)":::"memory"); }
    __builtin_amdgcn_s_barrier();
    __builtin_amdgcn_sched_barrier(0);
    bf16x8 ah[4], al[4], bh[4], bl[4];
    #pragma unroll
    for(int m=0;m<4;m++){
      int arow=wr*64+m*16+lq;
      int co = arow*32 + ((lg ^ ((arow>>1)&3)))*8;
      ah[m]=*(const bf16x8*)&Ahs[cur][co];
      al[m]=*(const bf16x8*)&Als[cur][co];
    }
    #pragma unroll
    for(int n=0;n<4;n++){
      int brow=wc*64+n*16+lq;
      int co = brow*32 + ((lg ^ ((brow>>1)&3)))*8;
      bh[n]=*(const bf16x8*)&Bhs[cur][co];
      bl[n]=*(const bf16x8*)&Bls[cur][co];
    }
    #pragma unroll
    for(int m=0;m<4;m++)
      #pragma unroll
      for(int n=0;n<4;n++){
        acc[m][n]=MFMA16(ah[m],bh[n],acc[m][n]);
        acc[m][n]=MFMA16(ah[m],bl[n],acc[m][n]);
        acc[m][n]=MFMA16(al[m],bh[n],acc[m][n]);
      }
    __builtin_amdgcn_s_barrier();
  }
  #undef STG
  #pragma unroll
  for(int m=0;m<4;m++){
    #pragma unroll
    for(int n=0;n<4;n++){
      int col = n0 + wc*64 + n*16 + lq;
      if(col<N){
        #pragma unroll
        for(int r=0;r<4;r++){
          int row = m0 + wr*64 + m*16 + lg*4 + r;
          float val = acc[m][n][r];
          if(EPI==0){
            int dc = (col<144)? col : col+16;
            u16 hh=f2b(val);
            Chi[(long)row*ldc + dc] = hh;
            Clo[(long)row*ldc + dc] = f2b(val-b2f(hh));
          } else if(EPI==1){
            (C32 + (long)z*cStrideZ)[(long)row*ldc + col] = val;
          } else {
            C32[(long)row*ldc+col] = resid[(long)row*ldc+col] + val;
          }
        }
      }
    }
  }
}

// ---------------- RoPE + hi/lo split repack ----------------
__global__ void k_ropesplit(const float* __restrict__ QR, const float* __restrict__ KR,
                            const float* __restrict__ cost, const float* __restrict__ sint,
                            u16* __restrict__ QHI, u16* __restrict__ QLO,
                            u16* __restrict__ KHI, u16* __restrict__ KLO){
  int i = blockIdx.x*256+threadIdx.x;
  if(i >= NT_*H_*32) return;
  int d = i&31; int h=(i>>5)%H_; int t = i/(H_*32);
  int s = t & (S_-1); int b = t >> 10;
  float c = cost[s*32+d], sn = sint[s*32+d];
  long qi = (long)t*D_ + h*HD_ + d;
  float q1=QR[qi], q2=QR[qi+32];
  float k1=KR[qi], k2=KR[qi+32];
  long ob = ((long)(b*H_+h)*S_ + s)*HD_ + d;
  float qa=(q1*c - q2*sn)*0.125f, qb2=(q2*c + q1*sn)*0.125f;
  float ka=k1*c - k2*sn,          kb2=k2*c + k1*sn;
  u16 hh;
  hh=f2b(qa);  QHI[ob]=hh;    QLO[ob]   =f2b(qa -b2f(hh));
  hh=f2b(qb2); QHI[ob+32]=hh; QLO[ob+32]=f2b(qb2-b2f(hh));
  hh=f2b(ka);  KHI[ob]=hh;    KLO[ob]   =f2b(ka -b2f(hh));
  hh=f2b(kb2); KHI[ob+32]=hh; KLO[ob+32]=f2b(kb2-b2f(hh));
}

// ---------------- V transpose + hi/lo split: [b][s][576] -> [bh][64][S] --
__global__ __launch_bounds__(256) void k_vsplit(const float* __restrict__ VR,
                       u16* __restrict__ VHI, u16* __restrict__ VLO){
  __shared__ float ls[64][65];
  int s0 = blockIdx.x*64; int bh = blockIdx.y;
  int b = bh/H_, h = bh - b*H_;
  int tid=threadIdx.x;
  #pragma unroll
  for(int i=0;i<16;i++){
    int idx = tid + i*256;
    int si = idx>>6, dj = idx&63;
    ls[si][dj] = VR[((long)(b*S_+s0+si))*D_ + h*HD_ + dj];
  }
  __syncthreads();
  #pragma unroll
  for(int i=0;i<16;i++){
    int idx = tid + i*256;
    int di = idx>>6, sj = idx&63;
    float v = ls[sj][di];
    u16 hh = f2b(v);
    long o = ((long)bh*HD_+di)*S_ + s0+sj;
    VHI[o]=hh; VLO[o]=f2b(v-b2f(hh));
  }
}

// ---------------- split-bf16 MFMA flash attention v3 -------------------
__global__ __launch_bounds__(256) void k_attn_split(
    const u16* __restrict__ QHI, const u16* __restrict__ QLO,
    const u16* __restrict__ KHI, const u16* __restrict__ KLO,
    const u16* __restrict__ VHI, const u16* __restrict__ VLO,
    u16* __restrict__ OHI, u16* __restrict__ OLO){
  __shared__ u16 lds[2][4][64*64];   // [buf][Khi,Klo,Vhi,Vlo][row*64]
  int tid=threadIdx.x, wid=tid>>6, lane=tid&63;
  int bh=blockIdx.x; int b=bh/H_, h=bh-b*H_;
  int jb=blockIdx.y;
  int lq=lane&15, lg=lane>>4;
  int jslot=lane&7, rloc=lane>>3;

  for(int pass=0;pass<2;pass++){
    int tile = pass? (15-jb) : jb;
    int ntile = tile+1;
    int q0 = tile*64 + wid*16;
    long qoff = ((long)bh*S_ + q0+lq)*HD_;
    bf16x8 qh0 = *(const bf16x8*)(QHI+qoff+lg*8);
    bf16x8 qh1 = *(const bf16x8*)(QHI+qoff+32+lg*8);
    bf16x8 ql0 = *(const bf16x8*)(QLO+qoff+lg*8);
    bf16x8 ql1 = *(const bf16x8*)(QLO+qoff+32+lg*8);
    float m=-1e30f, l=0.f;
    f32x4 ot[4]={};
    int q_lane = q0 + lq;

    #define STAGE(bufi, kv0_) do{                                          \
      int _kv0=(kv0_);                                                     \
      _Pragma("unroll")                                                    \
      for(int c=0;c<2;c++){                                                \
        int r = wid*16 + c*8 + rloc;                                       \
        int col = 8*(jslot ^ (r&7));                                       \
        long kg = ((long)bh*S_ + _kv0 + r)*64 + col;                       \
        long vg = ((long)bh*64 + r)*S_ + _kv0 + col;                       \
        int lb = (wid*16 + c*8)*64;                                        \
        gll16(KHI+kg, &lds[bufi][0][lb]);                                  \
        gll16(KLO+kg, &lds[bufi][1][lb]);                                  \
        gll16(VHI+vg, &lds[bufi][2][lb]);                                  \
        gll16(VLO+vg, &lds[bufi][3][lb]);                                  \
      } }while(0)

    STAGE(0, 0);
    __syncthreads();
    for(int t=0;t<ntile;t++){
      if(t+1<ntile) STAGE((t+1)&1, (t+1)*64);
      int bufc = t&1;
      int kv0 = t*64;
      bool last = (t==ntile-1);
      const char* Khs=(const char*)lds[bufc][0];
      const char* Kls=(const char*)lds[bufc][1];
      const char* Vhs=(const char*)lds[bufc][2];
      const char* Vls=(const char*)lds[bufc][3];
      #pragma unroll
      for(int kvh=0;kvh<64;kvh+=32){
        float p[8];
        float tmax=-1e30f;
        #pragma unroll
        for(int sub=0;sub<2;sub++){
          int r = kvh + sub*16 + lq;
          int sw = (r&7)<<4;
          bf16x8 kh0=*(const bf16x8*)(Khs + r*128 + ((lg*16) ^ sw));
          bf16x8 kh1=*(const bf16x8*)(Khs + r*128 + ((64+lg*16) ^ sw));
          bf16x8 kl0=*(const bf16x8*)(Kls + r*128 + ((lg*16) ^ sw));
          bf16x8 kl1=*(const bf16x8*)(Kls + r*128 + ((64+lg*16) ^ sw));
          f32x4 st={0.f,0.f,0.f,0.f};
          st=MFMA16(kh0,qh0,st); st=MFMA16(kh1,qh1,st);
          st=MFMA16(kl0,qh0,st); st=MFMA16(kl1,qh1,st);
          st=MFMA16(kh0,ql0,st); st=MFMA16(kh1,ql1,st);
          #pragma unroll
          for(int r2=0;r2<4;r2++){
            int key = kv0 + kvh + sub*16 + lg*4 + r2;
            float sv = (!last || key <= q_lane)? st[r2] : -1e30f;
            p[sub*4+r2]=sv;
            tmax = fmaxf(tmax, sv);
          }
        }
        tmax = fmaxf(tmax, __shfl_xor(tmax,16,64));
        tmax = fmaxf(tmax, __shfl_xor(tmax,32,64));
        float mn = fmaxf(m, tmax);
        float sc = __expf(m - mn);
        l *= sc;
        #pragma unroll
        for(int t2=0;t2<4;t2++)
          #pragma unroll
          for(int r2=0;r2<4;r2++) ot[t2][r2]*=sc;
        float ps=0.f;
        #pragma unroll
        for(int j=0;j<8;j++){ p[j]=__expf(p[j]-mn); ps+=p[j]; }
        l+=ps; m=mn;
        bf16x8 ph, pl;
        #pragma unroll
        for(int j=0;j<8;j++){
          u16 hb2=f2b(p[j]);
          ph[j]=(short)hb2;
          pl[j]=(short)f2b(p[j]-b2f(hb2));
        }
        #pragma unroll
        for(int t2=0;t2<4;t2++){
          int d = t2*16+lq;
          int swd = (d&7)<<4;
          int b1 = (2*(kvh+4*lg)) ^ swd;
          int b2v = (2*(kvh+16+4*lg)) ^ swd;
          us4 vh0=*(const us4*)(Vhs + d*128 + b1);
          us4 vh1=*(const us4*)(Vhs + d*128 + b2v);
          us4 vl0=*(const us4*)(Vls + d*128 + b1);
          us4 vl1=*(const us4*)(Vls + d*128 + b2v);
          bf16x8 vh, vl;
          #pragma unroll
          for(int j=0;j<4;j++){
            vh[j]=(short)vh0[j]; vh[4+j]=(short)vh1[j];
            vl[j]=(short)vl0[j]; vl[4+j]=(short)vl1[j];
          }
          ot[t2]=MFMA16(vh,ph,ot[t2]);
          ot[t2]=MFMA16(vl,ph,ot[t2]);
          ot[t2]=MFMA16(vh,pl,ot[t2]);
        }
      }
      __syncthreads();
    }
    #undef STAGE
    float l1 = l + __shfl_xor(l,16,64);
    float lt = l1 + __shfl_xor(l1,32,64);
    float inv = 1.f/lt;
    long orow = ((long)b*S_ + q_lane)*D_ + h*HD_;
    #pragma unroll
    for(int t2=0;t2<4;t2++){
      us4 oh4, ol4;
      #pragma unroll
      for(int r2=0;r2<4;r2++){
        float v=ot[t2][r2]*inv;
        u16 hh=f2b(v);
        oh4[r2]=hh; ol4[r2]=f2b(v-b2f(hh));
      }
      *(us4*)(OHI + orow + t2*16 + 4*lg) = oh4;
      *(us4*)(OLO + orow + t2*16 + 4*lg) = ol4;
    }
  }
}

// ---------------- expert histogram (LDS, 7 global atomics/block) -------
__global__ __launch_bounds__(256) void k_count(const int* __restrict__ idx2, int* __restrict__ counts){
  __shared__ int hist[NE_];
  int tid=threadIdx.x;
  if(tid<NE_) hist[tid]=0;
  __syncthreads();
  int i = blockIdx.x*256+tid;
  atomicAdd(&hist[idx2[i]],1);
  __syncthreads();
  if(tid<NE_) atomicAdd(&counts[tid], hist[tid]);
}

// offsets + flattened tile table (ts[0..7]=tile start per group, ts[8]=total)
__global__ void k_offsets(const int* __restrict__ counts, int* __restrict__ ofs,
                          int* __restrict__ fill, int* __restrict__ ts){
  if(threadIdx.x==0 && blockIdx.x==0){
    int a=0;
    for(int e=0;e<NE_;e++){ ofs[e]=a; fill[e]=a; a+=counts[e]; }
    ofs[NE_]=a;
    int t=0;
    for(int e=0;e<NE_;e++){ ts[e]=t; t += (counts[e]+127)>>7; }
    ts[NE_]=t; t+=64;          // shared expert: 64 m-tiles
    ts[NE_+1]=t;
  }
}

// ---------------- ballot-scan scatter (1 atomic/expert/block) ----------
__global__ __launch_bounds__(256) void k_scatter2(const int* __restrict__ idx2, const float* __restrict__ w2,
                          int* __restrict__ fill, int* __restrict__ ltok,
                          float* __restrict__ lw, int* __restrict__ ppos){
  __shared__ int wcnt[4][8];
  __shared__ int wpre[4][8];
  __shared__ int base[8];
  int tid=threadIdx.x, wid=tid>>6, lane=tid&63;
  int slot = blockIdx.x*256 + wid*64 + lane;
  int id = idx2[slot];
  unsigned long long ltm = (1ull<<lane)-1ull;
  int myrank=0;
  #pragma unroll
  for(int e=0;e<7;e++){
    unsigned long long mask = __ballot(id==e);
    if(id==e) myrank = __popcll(mask & ltm);
    if(lane==0) wcnt[wid][e] = __popcll(mask);
  }
  __syncthreads();
  if(wid==0 && lane<7){
    int e=lane;
    int s0=wcnt[0][e], s1=wcnt[1][e], s2=wcnt[2][e], s3=wcnt[3][e];
    wpre[0][e]=0; wpre[1][e]=s0; wpre[2][e]=s0+s1; wpre[3][e]=s0+s1+s2;
    base[e] = atomicAdd(&fill[e], s0+s1+s2+s3);
  }
  __syncthreads();
  int pos = base[id] + wpre[wid][id] + myrank;
  ltok[pos] = slot>>1;
  lw[pos] = w2[slot];
  ppos[slot] = pos;
}

// ---------------- grouped gate+up+SwiGLU (counted-vmcnt pipeline) ------
__global__ __launch_bounds__(256) void k_moe_gu(const u16* __restrict__ h2b, const u16* __restrict__ Gb,
                        const u16* __restrict__ Ub, const int* __restrict__ cnt,
                        const int* __restrict__ ofs, const int* __restrict__ ts,
                        const int* __restrict__ ltok, u16* __restrict__ act){
  int tsv[9];
  #pragma unroll
  for(int i=0;i<9;i++) tsv[i]=ts[i];
  int xt = blockIdx.y;
  if(xt >= tsv[8]) return;
  int e=0;
  #pragma unroll
  for(int i=1;i<8;i++) if(xt >= tsv[i]) e=i;
  int mt = xt - tsv[e];
  int nrows = (e<NE_)? cnt[e] : NT_;
  int base  = (e<NE_)? ofs[e] : 0;
  long arow0 = (e<NE_)? (long)base : (long)NPAIR_;
  int f0 = blockIdx.x*128;
  __shared__ u16 As[2][128*32], Gs[2][128*32], Us[2][128*32];
  int tid=threadIdx.x, wid=tid>>6, lane=tid&63;
  int lq=lane&15, lg=lane>>4;
  int wr=wid>>1, wc=wid&1;
  int r0 = wid*16 + (lane>>2);
  int r1 = 64 + r0;
  int so = wid*1024 + lane*16;
  int sc8 = ((lane&3) ^ ((r0>>1)&3))*8;
  int ri0 = mt*128+r0; if(ri0>nrows-1) ri0=nrows-1;
  int ri1 = mt*128+r1; if(ri1>nrows-1) ri1=nrows-1;
  long tok0 = (e<NE_)? (long)ltok[base+ri0] : (long)ri0;
  long tok1 = (e<NE_)? (long)ltok[base+ri1] : (long)ri1;
  const u16* a0 = h2b + tok0*D_ + sc8;
  const u16* a1 = h2b + tok1*D_ + sc8;
  const u16* g0 = Gb + ((long)e*FF_ + f0 + r0)*D_ + sc8;
  const u16* g1 = Gb + ((long)e*FF_ + f0 + r1)*D_ + sc8;
  const u16* u0 = Ub + ((long)e*FF_ + f0 + r0)*D_ + sc8;
  const u16* u1 = Ub + ((long)e*FF_ + f0 + r1)*D_ + sc8;
  #define STG(bi, kt_) do{ int ko=(kt_)*32;                       \
    gll16(a0+ko, (char*)As[bi]+so);                               \
    gll16(a1+ko, (char*)As[bi]+4096+so);                          \
    gll16(g0+ko, (char*)Gs[bi]+so);                               \
    gll16(g1+ko, (char*)Gs[bi]+4096+so);                          \
    gll16(u0+ko, (char*)Us[bi]+so);                               \
    gll16(u1+ko, (char*)Us[bi]+4096+so); }while(0)
  f32x4 ag_[4][4]={}, au_[4][4]={};
  STG(0,0);
  for(int kt=0;kt<18;kt++){
    int cur = kt&1;
    if(kt<17){ STG(cur^1, kt+1); asm volatile("s_waitcnt vmcnt(6)":::"memory"); }
    else     { asm volatile("s_waitcnt vmcnt(0)":::"memory"); }
    __builtin_amdgcn_s_barrier();
    __builtin_amdgcn_sched_barrier(0);
    bf16x8 af[4], gf[4], uf[4];
    #pragma unroll
    for(int m=0;m<4;m++){
      int arow=wr*64+m*16+lq;
      af[m]=*(const bf16x8*)&As[cur][arow*32 + ((lg ^ ((arow>>1)&3)))*8];
    }
    #pragma unroll
    for(int n=0;n<4;n++){
      int grow=wc*64+n*16+lq;
      int co = grow*32 + ((lg ^ ((grow>>1)&3)))*8;
      gf[n]=*(const bf16x8*)&Gs[cur][co];
      uf[n]=*(const bf16x8*)&Us[cur][co];
    }
    #pragma unroll
    for(int m=0;m<4;m++)
      #pragma unroll
      for(int n=0;n<4;n++){
        ag_[m][n]=MFMA16(af[m],gf[n],ag_[m][n]);
        au_[m][n]=MFMA16(af[m],uf[n],au_[m][n]);
      }
    __builtin_amdgcn_s_barrier();
  }
  #undef STG
  #pragma unroll
  for(int m=0;m<4;m++){
    #pragma unroll
    for(int n=0;n<4;n++){
      int f = f0 + wc*64+n*16+lq;
      #pragma unroll
      for(int r=0;r<4;r++){
        int rl = wr*64+m*16+lg*4+r;
        int ridx = mt*128+rl;
        if(ridx<nrows){
          float g=ag_[m][n][r], u=au_[m][n][r];
          float sw = g/(1.f+__expf(-g))*u;
          act[(arow0+ridx)*FF_ + f] = f2b(sw);
        }
      }
    }
  }
}

// ---------------- grouped down-proj (counted-vmcnt pipeline) -----------
__global__ __launch_bounds__(256) void k_moe_down(const u16* __restrict__ act, const u16* __restrict__ Db,
                          const int* __restrict__ cnt, const int* __restrict__ ofs,
                          const int* __restrict__ ts, const float* __restrict__ lw,
                          u16* __restrict__ pd){
  int tsv[9];
  #pragma unroll
  for(int i=0;i<9;i++) tsv[i]=ts[i];
  int xt = blockIdx.y;
  if(xt >= tsv[8]) return;
  int e=0;
  #pragma unroll
  for(int i=1;i<8;i++) if(xt >= tsv[i]) e=i;
  int mt = xt - tsv[e];
  int nrows=(e<NE_)?cnt[e]:NT_;
  long arow0=(e<NE_)?(long)ofs[e]:(long)NPAIR_;
  int n0=blockIdx.x*128;
  __shared__ u16 As[2][128*32], Bs[2][128*32];
  int tid=threadIdx.x,wid=tid>>6,lane=tid&63;
  int lq=lane&15,lg=lane>>4;
  int wr=wid>>1,wc=wid&1;
  int r0 = wid*16 + (lane>>2);
  int r1 = 64 + r0;
  int so = wid*1024 + lane*16;
  int sc8 = ((lane&3) ^ ((r0>>1)&3))*8;
  int ri0 = mt*128+r0; if(ri0>nrows-1) ri0=nrows-1;
  int ri1 = mt*128+r1; if(ri1>nrows-1) ri1=nrows-1;
  const u16* a0 = act + (arow0+ri0)*FF_ + sc8;
  const u16* a1 = act + (arow0+ri1)*FF_ + sc8;
  int rb0 = n0+r0; if(rb0>D_-1) rb0=D_-1;
  int rb1 = n0+r1; if(rb1>D_-1) rb1=D_-1;
  const u16* b0p = Db + ((long)e*D_ + rb0)*FF_ + sc8;
  const u16* b1p = Db + ((long)e*D_ + rb1)*FF_ + sc8;
  #define STG(bi, kt_) do{ int ko=(kt_)*32;                       \
    gll16(a0+ko, (char*)As[bi]+so);                               \
    gll16(a1+ko, (char*)As[bi]+4096+so);                          \
    gll16(b0p+ko, (char*)Bs[bi]+so);                              \
    gll16(b1p+ko, (char*)Bs[bi]+4096+so); }while(0)
  f32x4 acc[4][4]={};
  STG(0,0);
  for(int kt=0;kt<48;kt++){
    int cur = kt&1;
    if(kt<47){ STG(cur^1, kt+1); asm volatile("s_waitcnt vmcnt(4)":::"memory"); }
    else     { asm volatile("s_waitcnt vmcnt(0)":::"memory"); }
    __builtin_amdgcn_s_barrier();
    __builtin_amdgcn_sched_barrier(0);
    bf16x8 af[4],bf2[4];
    #pragma unroll
    for(int m=0;m<4;m++){
      int arow=wr*64+m*16+lq;
      af[m]=*(const bf16x8*)&As[cur][arow*32 + ((lg ^ ((arow>>1)&3)))*8];
    }
    #pragma unroll
    for(int n=0;n<4;n++){
      int brow=wc*64+n*16+lq;
      bf2[n]=*(const bf16x8*)&Bs[cur][brow*32 + ((lg ^ ((brow>>1)&3)))*8];
    }
    #pragma unroll
    for(int m=0;m<4;m++)
      #pragma unroll
      for(int n=0;n<4;n++)
        acc[m][n]=MFMA16(af[m],bf2[n],acc[m][n]);
    __builtin_amdgcn_s_barrier();
  }
  #undef STG
  #pragma unroll
  for(int m=0;m<4;m++){
    #pragma unroll
    for(int n=0;n<4;n++){
      int col=n0+wc*64+n*16+lq;
      if(col<D_){
        #pragma unroll
        for(int r=0;r<4;r++){
          int rl=wr*64+m*16+lg*4+r;
          int ridx=mt*128+rl;
          if(ridx<nrows){
            float w=1.f;
            if(e<NE_) w=lw[arow0+ridx];
            pd[(arow0+ridx)*D_ + col]=f2b(w*acc[m][n][r]);
          }
        }
      }
    }
  }
}

// ---------------- final combine ----------------
__global__ void k_final(const float* __restrict__ x2, const u16* __restrict__ pd,
                        const int* __restrict__ ppos, float* __restrict__ out){
  int i=blockIdx.x*256+threadIdx.x;
  int tot = NT_*(D_/4);
  if(i>=tot) return;
  int t = i/(D_/4); int c = (i - t*(D_/4))*4;
  int p0=ppos[2*t], p1=ppos[2*t+1];
  const u16* a=pd+((long)NPAIR_+t)*D_+c;
  const u16* b=pd+(long)p0*D_+c;
  const u16* d=pd+(long)p1*D_+c;
  const float* xr = x2+(long)t*D_+c;
  float* o = out+(long)t*D_+c;
  #pragma unroll
  for(int j=0;j<4;j++) o[j]=xr[j]+b2f(a[j])+b2f(b[j])+b2f(d[j]);
}

extern "C" void kernel_launch(void* const* d_in, const int* in_sizes, int n_in,
                              void* d_out, int out_size, void* d_ws, size_t ws_size,
                              hipStream_t stream){
  const float* x    =(const float*)d_in[0];
  const float* ln1  =(const float*)d_in[1];
  const float* ln2  =(const float*)d_in[2];
  const float* Wqd  =(const float*)d_in[3];
  const float* Wkvd =(const float*)d_in[4];
  const float* Wqu  =(const float*)d_in[5];
  const float* Wku  =(const float*)d_in[6];
  const float* Wvu  =(const float*)d_in[7];
  const float* Wo   =(const float*)d_in[8];
  const float* sg   =(const float*)d_in[9];
  const float* su   =(const float*)d_in[10];
  const float* sd   =(const float*)d_in[11];
  const float* rg   =(const float*)d_in[12];
  const float* ru   =(const float*)d_in[13];
  const float* rd   =(const float*)d_in[14];
  const float* Wr   =(const float*)d_in[15];
  const float* rb   =(const float*)d_in[16];
  float* out=(float*)d_out;

  char* ws=(char*)d_ws;
  size_t off=0;
  auto alloc=[&](size_t bsz){ size_t r=off; off=(off+bsz+255)&~(size_t)255; return r; };
  // fixed region
  u16* GB   =(u16*)(ws+alloc(8L*FF_*D_*2));
  u16* UB   =(u16*)(ws+alloc(8L*FF_*D_*2));
  u16* DB   =(u16*)(ws+alloc(8L*D_*FF_*2));
  float* COS=(float*)(ws+alloc(S_*32*4));
  float* SIN=(float*)(ws+alloc(S_*32*4));
  float* X2 =(float*)(ws+alloc((long)NT_*D_*4));
  u16* H2B  =(u16*)(ws+alloc((long)NT_*D_*2));
  int* IDX2 =(int*)(ws+alloc(NT_*2*4));
  float* W2 =(float*)(ws+alloc(NT_*2*4));
  int* PPOS =(int*)(ws+alloc(NT_*2*4));
  int* CNT  =(int*)(ws+alloc(64));
  int* OFS  =(int*)(ws+alloc(64));
  int* FILL =(int*)(ws+alloc(64));
  int* TS   =(int*)(ws+alloc(64));
  int* LTOK =(int*)(ws+alloc(NPAIR_*4));
  float* LW =(float*)(ws+alloc(NPAIR_*4));
  size_t scr0 = off;
  // phase A (attention)
  const long NQ = (long)B_*H_*S_*HD_;   // 4.72M elems
  u16* H1HI=(u16*)(ws+alloc((long)NT_*D_*2));
  u16* H1LO=(u16*)(ws+alloc((long)NT_*D_*2));
  u16* LATHI=(u16*)(ws+alloc((long)NT_*320*2));
  u16* LATLO=(u16*)(ws+alloc((long)NT_*320*2));
  float* QR =(float*)(ws+alloc((long)NT_*D_*4));
  float* KR =(float*)(ws+alloc((long)NT_*D_*4));
  float* VR =(float*)(ws+alloc((long)NT_*D_*4));
  u16* QHI =(u16*)(ws+alloc(NQ*2));
  u16* QLO =(u16*)(ws+alloc(NQ*2));
  u16* KHI =(u16*)(ws+alloc(NQ*2));
  u16* KLO =(u16*)(ws+alloc(NQ*2));
  u16* WDHI=(u16*)(ws+alloc(288L*D_*2));
  u16* WDLO=(u16*)(ws+alloc(288L*D_*2));
  u16* WUPHI=(u16*)(ws+alloc(3L*D_*160*2));
  u16* WUPLO=(u16*)(ws+alloc(3L*D_*160*2));
  u16* WOHI=(u16*)(ws+alloc((long)D_*D_*2));
  u16* WOLO=(u16*)(ws+alloc((long)D_*D_*2));
  u16* VHI = (u16*)QR;
  u16* VLO = (u16*)QR + NQ;
  u16* OHI = H1HI;
  u16* OLO = H1LO;
  // phase B (MoE) overlaps phase A
  off = scr0;
  u16* ACT =(u16*)(ws+alloc((long)NACT_*FF_*2));
  u16* PD  =(u16*)(ws+alloc((long)NACT_*D_*2));
  (void)ws_size;

  // MoE weight conversion (plain bf16)
  CvtSegs cs;
  {
    const float* ss[6]={rg,sg,ru,su,rd,sd};
    u16* dd[6]={GB, GB+7L*FF_*D_, UB, UB+7L*FF_*D_, DB, DB+7L*D_*FF_};
    long nn[6]={7L*FF_*D_,(long)FF_*D_,7L*FF_*D_,(long)FF_*D_,7L*D_*FF_,(long)D_*FF_};
    cs.start4[0]=0;
    for(int j=0;j<6;j++){ cs.src[j]=ss[j]; cs.dst[j]=dd[j]; cs.start4[j+1]=cs.start4[j]+(int)(nn[j]/4); }
  }
  k_cvt<<<2048,256,0,stream>>>(cs);
  // attention weight conversion (hi/lo split)
  CvtSegs2 c2;
  {
    const float* ss[3]={Wqd, Wkvd, Wo};
    u16* dh[3]={WDHI, WDHI+144L*D_, WOHI};
    u16* dl[3]={WDLO, WDLO+144L*D_, WOLO};
    long nn[3]={144L*D_, 144L*D_, (long)D_*D_};
    c2.start4[0]=0;
    for(int j=0;j<3;j++){ c2.src[j]=ss[j]; c2.dhi[j]=dh[j]; c2.dlo[j]=dl[j]; c2.start4[j+1]=c2.start4[j]+(int)(nn[j]/4); }
  }
  k_cvt_split<<<512,256,0,stream>>>(c2);
  k_cvt_pad_split<<<(3*D_*160+255)/256,256,0,stream>>>(Wqu,Wku,Wvu,WUPHI,WUPLO);
  k_rope_tab<<<(S_*32+255)/256,256,0,stream>>>(COS,SIN);

  // attention block (split-bf16 MFMA throughout)
  k_rms<<<NT_,64,0,stream>>>(x, ln1, H1HI, H1LO);
  k_gemm2<0><<<dim3(64,3,1),256,0,stream>>>(H1HI,H1LO,D_,0, WDHI,WDLO,D_,0, 288,18, LATHI,LATLO,320, nullptr,0,nullptr);
  k_gemm2<1><<<dim3(64,5,3),256,0,stream>>>(LATHI,LATLO,320,160, WUPHI,WUPLO,160,(long)D_*160, D_,5, nullptr,nullptr,D_, QR,(long)NT_*D_, nullptr);
  k_ropesplit<<<(NT_*H_*32+255)/256,256,0,stream>>>(QR,KR,COS,SIN,QHI,QLO,KHI,KLO);
  k_vsplit<<<dim3(16,72),256,0,stream>>>(VR,VHI,VLO);
  k_attn_split<<<dim3(72,8),256,0,stream>>>(QHI,QLO,KHI,KLO,VHI,VLO,OHI,OLO);
  k_gemm2<2><<<dim3(64,5,1),256,0,stream>>>(OHI,OLO,D_,0, WOHI,WOLO,D_,0, D_,18, nullptr,nullptr,D_, X2,0, x);

  // MoE block
  hipMemsetAsync(CNT,0,64,stream);
  k_rms_router<<<NT_/4,256,0,stream>>>(X2, ln2, Wr, rb, H2B, IDX2, W2);
  k_count<<<NPAIR_/256,256,0,stream>>>(IDX2,CNT);
  k_offsets<<<1,1,0,stream>>>(CNT,OFS,FILL,TS);
  k_scatter2<<<NPAIR_/256,256,0,stream>>>(IDX2,W2,FILL,LTOK,LW,PPOS);
  k_moe_gu<<<dim3(12,MAXT_),256,0,stream>>>(H2B,GB,UB,CNT,OFS,TS,LTOK,ACT);
  k_moe_down<<<dim3(5,MAXT_),256,0,stream>>>(ACT,DB,CNT,OFS,TS,LW,PD);
  k_final<<<(NT_*(D_/4)+255)/256,256,0,stream>>>(X2,PD,PPOS,out);
}